// Round 1
// baseline (394.580 us; speedup 1.0000x reference)
//
#include <hip/hip_runtime.h>
#include <math.h>

// Problem constants (reference: M, N = 8192, 8192; H = N/2)
#define M_ROWS 8192
#define N_COLS 8192
#define H_COLS 4096

// One block per row. 256 threads x 16 elements = 4096 = H.
// Phase 1: load front/back halves as float4, compute s = qs * lin * silu(glu)
//          into registers, track per-thread absmax.
// Phase 2: wave64 shuffle max-reduce + LDS cross-wave reduce -> row absmax.
// Phase 3: quantize registers, store as float4 (int8 values stored as f32 per
//          harness output contract), thread 0 stores the row scale.
__global__ __launch_bounds__(256) void swiglu_quant_kernel(
    const float* __restrict__ x,
    const float* __restrict__ weight_scale,
    const float* __restrict__ activation_scale,
    const float* __restrict__ quant_scale,
    float* __restrict__ out_q,       // M*H floats (int8 values as f32)
    float* __restrict__ out_scale)   // M floats
{
    const int row = blockIdx.x;
    const int tid = threadIdx.x;

    const float c  = weight_scale[0] * activation_scale[row];
    const float qs = quant_scale[0];

    const float4* __restrict__ xf4 =
        reinterpret_cast<const float4*>(x + (size_t)row * N_COLS);
    const float4* __restrict__ xb4 =
        reinterpret_cast<const float4*>(x + (size_t)row * N_COLS + H_COLS);

    float s[16];
    float amax = 0.0f;

    #pragma unroll
    for (int it = 0; it < 4; ++it) {
        const int idx = it * 256 + tid;     // float4 index within the half-row
        float4 f = xf4[idx];
        float4 b = xb4[idx];
        const float* fp = reinterpret_cast<const float*>(&f);
        const float* bp = reinterpret_cast<const float*>(&b);
        #pragma unroll
        for (int k = 0; k < 4; ++k) {
            float lin = c * fp[k];
            float g   = c * bp[k];
            float sig = 1.0f / (1.0f + __expf(-g));
            float v   = qs * lin * (g * sig);
            s[it * 4 + k] = v;
            amax = fmaxf(amax, fabsf(v));
        }
    }

    // wave64 butterfly max
    #pragma unroll
    for (int off = 32; off > 0; off >>= 1)
        amax = fmaxf(amax, __shfl_down(amax, off, 64));

    __shared__ float wmax[4];
    const int lane = tid & 63;
    const int wave = tid >> 6;
    if (lane == 0) wmax[wave] = amax;
    __syncthreads();
    const float rowmax =
        fmaxf(fmaxf(wmax[0], wmax[1]), fmaxf(wmax[2], wmax[3]));

    const float scale = rowmax * (1.0f / 127.0f);
    // scale == 0 -> reference forces i8 = 0; inv = 0 achieves that.
    const float inv = (scale > 0.0f) ? (1.0f / scale) : 0.0f;

    if (tid == 0) out_scale[row] = scale;

    float4* __restrict__ oq =
        reinterpret_cast<float4*>(out_q + (size_t)row * H_COLS);
    #pragma unroll
    for (int it = 0; it < 4; ++it) {
        const int idx = it * 256 + tid;
        float4 o;
        float* op = reinterpret_cast<float*>(&o);
        #pragma unroll
        for (int k = 0; k < 4; ++k) {
            float q = rintf(s[it * 4 + k] * inv);   // nearest-even, like jnp.round
            q = fminf(fmaxf(q, -128.0f), 127.0f);
            op[k] = q;
        }
        oq[idx] = o;
    }
}

extern "C" void kernel_launch(void* const* d_in, const int* in_sizes, int n_in,
                              void* d_out, int out_size, void* d_ws, size_t ws_size,
                              hipStream_t stream) {
    const float* x  = (const float*)d_in[0];   // (M, N)
    const float* ws = (const float*)d_in[1];   // (N,)  -- only [0] used by ref
    const float* as = (const float*)d_in[2];   // (M, 1)
    const float* qs = (const float*)d_in[3];   // (1,)

    float* out_q     = (float*)d_out;                       // M*H
    float* out_scale = out_q + (size_t)M_ROWS * H_COLS;     // M

    swiglu_quant_kernel<<<dim3(M_ROWS), dim3(256), 0, stream>>>(
        x, ws, as, qs, out_q, out_scale);
}

// Round 3
// 373.936 us; speedup vs baseline: 1.0552x; 1.0552x over previous
//
#include <hip/hip_runtime.h>
#include <math.h>

// Problem constants (reference: M, N = 8192, 8192; H = N/2)
#define M_ROWS 8192
#define N_COLS 8192
#define H_COLS 4096

// Native vector type — __builtin_nontemporal_* requires a real vector, not
// HIP's HIP_vector_type class.
typedef float vf4 __attribute__((ext_vector_type(4)));

// One block (512 threads) per row; 8 elements/thread keeps register state low
// (s[8] + 4 float4 loads in flight ~ 40 VGPR -> 8 waves/SIMD occupancy).
// Streaming data: nontemporal loads/stores to avoid cache pollution.
// Sigmoid via fast v_rcp (exactness irrelevant: int8 round tolerance is +/-1,
// and the scale output shifts by <= ~2 ulp).
__global__ __launch_bounds__(512) void swiglu_quant_kernel(
    const float* __restrict__ x,
    const float* __restrict__ weight_scale,
    const float* __restrict__ activation_scale,
    const float* __restrict__ quant_scale,
    float* __restrict__ out_q,       // M*H floats (int8 values as f32)
    float* __restrict__ out_scale)   // M floats
{
    const int row = blockIdx.x;
    const int tid = threadIdx.x;

    const float c  = weight_scale[0] * activation_scale[row];
    const float qs = quant_scale[0];

    const vf4* __restrict__ xf4 =
        reinterpret_cast<const vf4*>(x + (size_t)row * N_COLS);
    const vf4* __restrict__ xb4 =
        reinterpret_cast<const vf4*>(x + (size_t)row * N_COLS + H_COLS);

    float s[8];
    float amax = 0.0f;

    #pragma unroll
    for (int it = 0; it < 2; ++it) {
        const int idx = it * 512 + tid;     // float4 index within the half-row
        vf4 f = __builtin_nontemporal_load(&xf4[idx]);
        vf4 b = __builtin_nontemporal_load(&xb4[idx]);
        #pragma unroll
        for (int k = 0; k < 4; ++k) {
            float lin = c * f[k];
            float g   = c * b[k];
            float e   = __expf(-g);                       // v_exp_f32 path
            float sig = __builtin_amdgcn_rcpf(1.0f + e);  // fast reciprocal
            float v   = qs * lin * (g * sig);
            s[it * 4 + k] = v;
            amax = fmaxf(amax, fabsf(v));
        }
    }

    // wave64 butterfly max
    #pragma unroll
    for (int off = 32; off > 0; off >>= 1)
        amax = fmaxf(amax, __shfl_down(amax, off, 64));

    __shared__ float wmax[8];
    const int lane = tid & 63;
    const int wave = tid >> 6;
    if (lane == 0) wmax[wave] = amax;
    __syncthreads();
    float rowmax = wmax[0];
    #pragma unroll
    for (int w = 1; w < 8; ++w) rowmax = fmaxf(rowmax, wmax[w]);

    const float scale = rowmax * (1.0f / 127.0f);
    // scale == 0 -> reference forces i8 = 0; inv = 0 achieves that.
    const float inv = (scale > 0.0f) ? (127.0f / rowmax) : 0.0f;

    if (tid == 0) out_scale[row] = scale;

    vf4* __restrict__ oq =
        reinterpret_cast<vf4*>(out_q + (size_t)row * H_COLS);
    #pragma unroll
    for (int it = 0; it < 2; ++it) {
        const int idx = it * 512 + tid;
        vf4 o;
        #pragma unroll
        for (int k = 0; k < 4; ++k) {
            float q = rintf(s[it * 4 + k] * inv);   // nearest-even, like jnp.round
            q = fminf(fmaxf(q, -128.0f), 127.0f);
            o[k] = q;
        }
        __builtin_nontemporal_store(o, &oq[idx]);
    }
}

extern "C" void kernel_launch(void* const* d_in, const int* in_sizes, int n_in,
                              void* d_out, int out_size, void* d_ws, size_t ws_size,
                              hipStream_t stream) {
    const float* x  = (const float*)d_in[0];   // (M, N)
    const float* ws = (const float*)d_in[1];   // (N,)  -- only [0] used by ref
    const float* as = (const float*)d_in[2];   // (M, 1)
    const float* qs = (const float*)d_in[3];   // (1,)

    float* out_q     = (float*)d_out;                       // M*H
    float* out_scale = out_q + (size_t)M_ROWS * H_COLS;     // M

    swiglu_quant_kernel<<<dim3(M_ROWS), dim3(512), 0, stream>>>(
        x, ws, as, qs, out_q, out_scale);
}